// Round 2
// baseline (342.480 us; speedup 1.0000x reference)
//
#include <hip/hip_runtime.h>
#include <hip/hip_bf16.h>

// MaskedRoIAlign: out[k,c,ph,pw] = mean over SR*SR bilinear samples of
// (features[b_k] * masks[k]) with torchvision RoIAlign edge handling.
// N=2, C=256, H=W=64, K=64, PH=PW=7, SCALE=0.25, SR=2. Output fp32.
//
// R1 design: gather->stream conversion. Per (box, 2-channel) block:
//   1) cooperatively stream the needed row range of features & masks with
//      coalesced float4 loads, multiply, store product rows to LDS;
//   2) each lane bilinear-gathers its 7x7 bin's 16 corners from LDS.
// This removes the address-divergent global gathers that made R0 340us.

constexpr int N_ = 2, C_ = 256, H_ = 64, W_ = 64;
constexpr int K_ = 64, PH_ = 7, PW_ = 7, SR_ = 2;
constexpr float SCALE_ = 0.25f;
constexpr int CG = 2;          // channels per block
constexpr int BT = 128;        // block threads (2 waves: wave i -> channel i)

__global__ __launch_bounds__(BT)
void masked_roialign_lds(const float* __restrict__ features,
                         const float* __restrict__ boxes,
                         const float* __restrict__ masks,
                         float* __restrict__ out) {
    __shared__ float prod[CG * H_ * W_];   // 2 * 4096 floats = 32 KB

    const int k  = blockIdx.x;             // box
    const int cg = blockIdx.y;             // channel group of CG
    const int t  = threadIdx.x;

    // Box parameters (uniform per block; cheap to recompute per thread).
    const float* bx = boxes + k * 5;
    const int   b  = (int)bx[0];
    const float x1 = bx[1] * SCALE_;
    const float y1 = bx[2] * SCALE_;
    const float x2 = bx[3] * SCALE_;
    const float y2 = bx[4] * SCALE_;
    const float roi_w = fmaxf(x2 - x1, 1.0f);
    const float roi_h = fmaxf(y2 - y1, 1.0f);
    const float bin_w = roi_w * (1.0f / PW_);
    const float bin_h = roi_h * (1.0f / PH_);

    // Row range covering all clamped sample rows (and their +1 neighbors).
    // Sample ys span [y1 + 0.25*bin_h, y1 + 6.75*bin_h] before clamping.
    const float ymin_c = fminf(fmaxf(y1 + 0.25f * bin_h, 0.0f), (float)(H_ - 1));
    const float ymax_c = fminf(fmaxf(y1 + 6.75f * bin_h, 0.0f), (float)(H_ - 1));
    const int ylo   = (int)ymin_c;
    const int yhi   = min((int)ymax_c + 1, H_ - 1);
    const int nrows = yhi - ylo + 1;       // 1..64

    // Phase 1: coalesced stream of full-width rows [ylo..yhi], product to LDS.
#pragma unroll
    for (int cl = 0; cl < CG; ++cl) {
        const int c = cg * CG + cl;
        const float4* __restrict__ f4 =
            (const float4*)(features + ((size_t)b * C_ + c) * (H_ * W_) + ylo * W_);
        const float4* __restrict__ m4 =
            (const float4*)(masks    + ((size_t)k * C_ + c) * (H_ * W_) + ylo * W_);
        float4* p4 = (float4*)(prod + cl * (H_ * W_));
        const int nvec = nrows * (W_ / 4);          // float4 chunks
        for (int i = t; i < nvec; i += BT) {
            const float4 fv = f4[i];
            const float4 mv = m4[i];
            p4[i] = make_float4(fv.x * mv.x, fv.y * mv.y, fv.z * mv.z, fv.w * mv.w);
        }
    }
    __syncthreads();

    // Phase 2: wave i handles channel cg*CG+i; lane = output bin (49 of 64).
    const int cl  = t >> 6;
    const int bin = t & 63;
    if (bin >= PH_ * PW_) return;
    const int ph = bin / PW_;
    const int pw = bin - ph * PW_;

    const float* __restrict__ p = prod + cl * (H_ * W_);

    float acc = 0.0f;
#pragma unroll
    for (int iy = 0; iy < SR_; ++iy) {
        const float y  = y1 + ((float)ph + ((float)iy + 0.5f) * 0.5f) * bin_h;
        const bool  vy = (y >= -1.0f) && (y <= (float)H_);
        const float yc = fminf(fmaxf(y, 0.0f), (float)(H_ - 1));
        const int   yl = (int)yc;
        const int   yh = min(yl + 1, H_ - 1);
        const float ly = yc - (float)yl;
        const float hy = 1.0f - ly;
        const int   rl = yl - ylo;          // in [0, nrows)
        const int   rh = yh - ylo;
#pragma unroll
        for (int ix = 0; ix < SR_; ++ix) {
            const float x  = x1 + ((float)pw + ((float)ix + 0.5f) * 0.5f) * bin_w;
            const bool  vx = (x >= -1.0f) && (x <= (float)W_);
            const float xc = fminf(fmaxf(x, 0.0f), (float)(W_ - 1));
            const int   xl = (int)xc;
            const int   xh = min(xl + 1, W_ - 1);
            const float lx = xc - (float)xl;
            const float hx = 1.0f - lx;

            const float v00 = p[rl * W_ + xl];
            const float v01 = p[rl * W_ + xh];
            const float v10 = p[rh * W_ + xl];
            const float v11 = p[rh * W_ + xh];
            const float val = hy * hx * v00 + hy * lx * v01
                            + ly * hx * v10 + ly * lx * v11;
            acc += (vy && vx) ? val : 0.0f;
        }
    }
    const int c = cg * CG + cl;
    out[(((size_t)k * C_ + c) * PH_ + ph) * PW_ + pw] = acc * 0.25f;
}

extern "C" void kernel_launch(void* const* d_in, const int* in_sizes, int n_in,
                              void* d_out, int out_size, void* d_ws, size_t ws_size,
                              hipStream_t stream) {
    const float* features = (const float*)d_in[0];  // [2,256,64,64]
    const float* boxes    = (const float*)d_in[1];  // [64,5]
    const float* masks    = (const float*)d_in[2];  // [64,256,64,64]
    float* out            = (float*)d_out;          // [64,256,7,7]

    dim3 grid(K_, C_ / CG);   // 64 x 128 blocks
    dim3 block(BT);
    masked_roialign_lds<<<grid, block, 0, stream>>>(features, boxes, masks, out);
}